// Round 1
// baseline (343.578 us; speedup 1.0000x reference)
//
#include <hip/hip_runtime.h>
#include <hip/hip_bf16.h>

// InfoNCE: a[4096,512], p[4096,512], n[16384,512] f32 -> 4 f32 scalars.
// Plan: normalize+cast bf16 -> MFMA gemm a@n^T with exp-rowsum epilogue (S[4096])
//       -> MFMA gemm a@p^T with loss epilogue -> finalize (colsum trick for means).
// ws layout: a_bf(4MB) p_bf(4MB) n_bf(16MB) | S[4096] csA[512] csP[512] csN[512] lsum[1]

#define D_DIM 512
#define B_ROWS 4096
#define P_ROWS 4096
#define N_ROWS 16384
#define INV_T 14.285714285714286f
#define EPS_L 1e-8f

typedef __hip_bfloat16 bf16;
typedef __attribute__((ext_vector_type(8))) short short8;   // 8 bf16 = 4 VGPRs (MFMA A/B frag)
typedef __attribute__((ext_vector_type(4))) float floatx4;  // MFMA C/D frag

__device__ __forceinline__ unsigned short f2bf(float f) {
    union { __hip_bfloat16 h; unsigned short u; } cv;
    cv.h = __float2bfloat16(f);
    return cv.u;
}

// ---------------- normalize rows (one wave per row) + cast to bf16 ----------------
__global__ void normalize_rows(const float* __restrict__ in, bf16* __restrict__ out, int rows) {
    int gw   = (blockIdx.x * blockDim.x + threadIdx.x) >> 6;
    int lane = threadIdx.x & 63;
    if (gw >= rows) return;
    const float4* rp = reinterpret_cast<const float4*>(in + (size_t)gw * D_DIM);
    float4 v0 = rp[lane];
    float4 v1 = rp[lane + 64];
    float ss = v0.x*v0.x + v0.y*v0.y + v0.z*v0.z + v0.w*v0.w
             + v1.x*v1.x + v1.y*v1.y + v1.z*v1.z + v1.w*v1.w;
#pragma unroll
    for (int off = 1; off < 64; off <<= 1) ss += __shfl_xor(ss, off);
    float inv = 1.0f / fmaxf(sqrtf(ss), 1e-12f);
    ushort4 o0, o1;
    o0.x = f2bf(v0.x * inv); o0.y = f2bf(v0.y * inv); o0.z = f2bf(v0.z * inv); o0.w = f2bf(v0.w * inv);
    o1.x = f2bf(v1.x * inv); o1.y = f2bf(v1.y * inv); o1.z = f2bf(v1.z * inv); o1.w = f2bf(v1.w * inv);
    ushort4* op = reinterpret_cast<ushort4*>(out + (size_t)gw * D_DIM);
    op[lane]      = o0;
    op[lane + 64] = o1;
}

// ---------------- column sums of normalized bf16 matrix (for mean_pos/mean_neg trick) ---
__global__ void col_sum(const bf16* __restrict__ in, float* __restrict__ out, int rows) {
    int c = threadIdx.x;  // 512 threads, one per column -> coalesced row reads
    float s = 0.f;
    for (int r = blockIdx.x; r < rows; r += gridDim.x)
        s += __bfloat162float(in[(size_t)r * D_DIM + c]);
    atomicAdd(&out[c], s);
}

// ---------------- MFMA GEMM with fused epilogue ----------------
#define BM 128
#define BN 128
#define BK 64

typedef const __attribute__((address_space(1))) unsigned int* as1_u32p;
typedef __attribute__((address_space(3))) unsigned int* as3_u32p;

__device__ __forceinline__ void load_lds16(const void* g, void* l) {
    // each lane writes 16B at (wave-uniform l) + lane*16
    __builtin_amdgcn_global_load_lds((as1_u32p)g, (as3_u32p)l, 16, 0, 0);
}

// EPI==0: C = A@Bm^T, S[row] += sum_col exp(C*invT)        (neg pass)
// EPI==1: loss_sum += sum(-log(exp(C*invT)/(exp+S[row])+eps)) (pos pass)
template <int EPI>
__global__ __launch_bounds__(256, 2) void gemm_epi(const bf16* __restrict__ A,
                                                   const bf16* __restrict__ Bm,
                                                   float* __restrict__ S,
                                                   float* __restrict__ loss_sum) {
    __shared__ bf16 As[BM * BK];  // 16 KB, swizzled 16B granules: (row, c stored at c^(row&7))
    __shared__ bf16 Bs[BN * BK];  // 16 KB

    const int tid  = threadIdx.x;
    const int lane = tid & 63;
    const int w    = tid >> 6;          // wave 0..3
    const int wm   = w >> 1, wn = w & 1;
    const int m0   = blockIdx.y * BM;
    const int n0   = blockIdx.x * BN;
    const int lr   = lane & 15;         // col-in-tile for frags
    const int q    = lane >> 4;         // quad 0..3

    floatx4 acc[4][4];
#pragma unroll
    for (int i = 0; i < 4; ++i)
#pragma unroll
        for (int j = 0; j < 4; ++j) acc[i][j] = (floatx4){0.f, 0.f, 0.f, 0.f};

    // staging: lane fetches row (rbase + lane>>3), 16B chunk (lane&7)^(lane>>3)  (XOR swizzle
    // folded into the gather since global_load_lds LDS dest is lane-contiguous)
    const int srow   = lane >> 3;            // 0..7
    const int schunk = (lane & 7) ^ srow;    // swizzled 16B chunk index 0..7

    for (int kt = 0; kt < D_DIM; kt += BK) {
        __syncthreads();  // prior ds_reads done before overwrite
#pragma unroll
        for (int i = 0; i < 4; ++i) {
            int rbase = w * 32 + i * 8;  // 8-aligned -> (row&7)==(lane>>3)
            const bf16* asrc = A + (size_t)(m0 + rbase + srow) * D_DIM + kt + schunk * 8;
            load_lds16(asrc, &As[rbase * BK]);
            const bf16* bsrc = Bm + (size_t)(n0 + rbase + srow) * D_DIM + kt + schunk * 8;
            load_lds16(bsrc, &Bs[rbase * BK]);
        }
        __syncthreads();  // staging drained (compiler emits vmcnt(0) before barrier)

#pragma unroll
        for (int ks = 0; ks < 2; ++ks) {
            short8 af[4], bfr[4];
            const int cl = ks * 4 + q;                 // 16B chunk within BK row
            const int so = (cl ^ (lane & 7)) * 8;      // unswizzle: row&7 == lane&7 here
#pragma unroll
            for (int rt = 0; rt < 4; ++rt) {
                int r = wm * 64 + rt * 16 + lr;
                af[rt] = *reinterpret_cast<const short8*>(&As[r * BK + so]);
            }
#pragma unroll
            for (int ct = 0; ct < 4; ++ct) {
                int r = wn * 64 + ct * 16 + lr;
                bfr[ct] = *reinterpret_cast<const short8*>(&Bs[r * BK + so]);
            }
#pragma unroll
            for (int rt = 0; rt < 4; ++rt)
#pragma unroll
                for (int ct = 0; ct < 4; ++ct)
                    acc[rt][ct] = __builtin_amdgcn_mfma_f32_16x16x32_bf16(af[rt], bfr[ct],
                                                                          acc[rt][ct], 0, 0, 0);
        }
    }

    // C/D layout: col = lane&15, row = (lane>>4)*4 + reg
    if (EPI == 0) {
#pragma unroll
        for (int rt = 0; rt < 4; ++rt) {
#pragma unroll
            for (int reg = 0; reg < 4; ++reg) {
                float v = 0.f;
#pragma unroll
                for (int ct = 0; ct < 4; ++ct) v += __expf(acc[rt][ct][reg] * INV_T);
                v += __shfl_xor(v, 1);
                v += __shfl_xor(v, 2);
                v += __shfl_xor(v, 4);
                v += __shfl_xor(v, 8);
                if (lr == 0) {
                    int row = m0 + wm * 64 + rt * 16 + q * 4 + reg;
                    atomicAdd(&S[row], v);
                }
            }
        }
    } else {
        float lsum = 0.f;
#pragma unroll
        for (int rt = 0; rt < 4; ++rt) {
#pragma unroll
            for (int reg = 0; reg < 4; ++reg) {
                int row = m0 + wm * 64 + rt * 16 + q * 4 + reg;
                float Sv = S[row];
#pragma unroll
                for (int ct = 0; ct < 4; ++ct) {
                    float pe = __expf(acc[rt][ct][reg] * INV_T);
                    lsum -= __logf(pe / (pe + Sv) + EPS_L);
                }
            }
        }
#pragma unroll
        for (int off = 1; off < 64; off <<= 1) lsum += __shfl_xor(lsum, off);
        if (lane == 0) atomicAdd(loss_sum, lsum);
    }
}

// ---------------- finalize: dots of column sums + scalar outputs ----------------
__global__ void finalize_k(const float* __restrict__ csA, const float* __restrict__ csP,
                           const float* __restrict__ csN, const float* __restrict__ lsum,
                           float* __restrict__ out) {
    int lane = threadIdx.x;  // 64
    float dp = 0.f, dn = 0.f;
    for (int c = lane; c < D_DIM; c += 64) {
        float av = csA[c];
        dp += av * csP[c];
        dn += av * csN[c];
    }
#pragma unroll
    for (int off = 1; off < 64; off <<= 1) {
        dp += __shfl_xor(dp, off);
        dn += __shfl_xor(dn, off);
    }
    if (lane == 0) {
        float mean_pos = dp * INV_T / ((float)B_ROWS * (float)P_ROWS);
        float mean_neg = dn * INV_T / ((float)B_ROWS * (float)N_ROWS);
        out[0] = lsum[0] / ((float)B_ROWS * (float)P_ROWS);
        out[1] = mean_pos;
        out[2] = mean_neg;
        out[3] = mean_pos - mean_neg;
    }
}

extern "C" void kernel_launch(void* const* d_in, const int* in_sizes, int n_in,
                              void* d_out, int out_size, void* d_ws, size_t ws_size,
                              hipStream_t stream) {
    const float* anc = (const float*)d_in[0];
    const float* pos = (const float*)d_in[1];
    const float* neg = (const float*)d_in[2];
    float* out = (float*)d_out;

    bf16* aB = (bf16*)d_ws;
    bf16* pB = aB + (size_t)B_ROWS * D_DIM;
    bf16* nB = pB + (size_t)P_ROWS * D_DIM;
    float* fsec = (float*)(nB + (size_t)N_ROWS * D_DIM);  // 24MB offset, aligned
    float* S    = fsec;               // 4096
    float* csA  = S + B_ROWS;         // 512
    float* csP  = csA + D_DIM;        // 512
    float* csN  = csP + D_DIM;        // 512
    float* lsum = csN + D_DIM;        // 1

    // ws is re-poisoned 0xAA before every launch -> zero accumulators
    hipMemsetAsync(fsec, 0, (B_ROWS + 3 * D_DIM + 1) * sizeof(float), stream);

    normalize_rows<<<B_ROWS / 4, 256, 0, stream>>>(anc, aB, B_ROWS);
    normalize_rows<<<P_ROWS / 4, 256, 0, stream>>>(pos, pB, P_ROWS);
    normalize_rows<<<N_ROWS / 4, 256, 0, stream>>>(neg, nB, N_ROWS);

    col_sum<<<128, 512, 0, stream>>>(aB, csA, B_ROWS);
    col_sum<<<128, 512, 0, stream>>>(pB, csP, P_ROWS);
    col_sum<<<128, 512, 0, stream>>>(nB, csN, N_ROWS);

    gemm_epi<0><<<dim3(N_ROWS / BN, B_ROWS / BM), 256, 0, stream>>>(aB, nB, S, nullptr);
    gemm_epi<1><<<dim3(P_ROWS / BN, B_ROWS / BM), 256, 0, stream>>>(aB, pB, S, lsum);

    finalize_k<<<1, 64, 0, stream>>>(csA, csP, csN, lsum, out);
}

// Round 2
// 319.532 us; speedup vs baseline: 1.0753x; 1.0753x over previous
//
#include <hip/hip_runtime.h>
#include <hip/hip_bf16.h>

// InfoNCE: a[4096,512], p[4096,512], n[16384,512] f32 -> 4 f32 scalars.
// R2: fused normalize+colsum (fp32, stride-16 atomic spread), 5 dispatches total,
//     gemm occupancy 2->4 blocks/CU via __launch_bounds__(256,4).
// ws layout: a_bf(4MB) p_bf(4MB) n_bf(16MB) | S[4096] csA[512*16] csP[512*16] csN[512*16] lsum[1]

#define D_DIM 512
#define B_ROWS 4096
#define P_ROWS 4096
#define N_ROWS 16384
#define INV_T 14.285714285714286f
#define EPS_L 1e-8f
#define CS_STRIDE 16  // colsum accumulators spread 64B apart -> atomics hit distinct lines

typedef __hip_bfloat16 bf16;
typedef __attribute__((ext_vector_type(8))) short short8;   // 8 bf16 = 4 VGPRs (MFMA A/B frag)
typedef __attribute__((ext_vector_type(4))) float floatx4;  // MFMA C/D frag

__device__ __forceinline__ unsigned short f2bf(float f) {
    union { __hip_bfloat16 h; unsigned short u; } cv;
    cv.h = __float2bfloat16(f);
    return cv.u;
}

// ---- fused: L2-normalize rows -> bf16, and accumulate fp32 column sums ----
// grid = 1024 blocks x 256 thr. Segments: b<256 -> A, b<512 -> P, else -> N.
__global__ __launch_bounds__(256) void norm_colsum(
        const float* __restrict__ a, const float* __restrict__ p, const float* __restrict__ n,
        bf16* __restrict__ aB, bf16* __restrict__ pB, bf16* __restrict__ nB,
        float* __restrict__ csA, float* __restrict__ csP, float* __restrict__ csN) {
    const float* in; bf16* outp; float* cs; int rows, nb, bseg;
    int b = blockIdx.x;
    if (b < 256)      { in = a; outp = aB; cs = csA; rows = B_ROWS; nb = 256; bseg = b; }
    else if (b < 512) { in = p; outp = pB; cs = csP; rows = P_ROWS; nb = 256; bseg = b - 256; }
    else              { in = n; outp = nB; cs = csN; rows = N_ROWS; nb = 512; bseg = b - 512; }

    const int wave = threadIdx.x >> 6;
    const int lane = threadIdx.x & 63;

    float cs0[4] = {0.f, 0.f, 0.f, 0.f};
    float cs1[4] = {0.f, 0.f, 0.f, 0.f};

    for (int chunk = bseg; chunk < (rows >> 2); chunk += nb) {
        int r = chunk * 4 + wave;
        const float4* rp = reinterpret_cast<const float4*>(in + (size_t)r * D_DIM);
        float4 v0 = rp[lane];
        float4 v1 = rp[lane + 64];
        float ss = v0.x*v0.x + v0.y*v0.y + v0.z*v0.z + v0.w*v0.w
                 + v1.x*v1.x + v1.y*v1.y + v1.z*v1.z + v1.w*v1.w;
#pragma unroll
        for (int off = 1; off < 64; off <<= 1) ss += __shfl_xor(ss, off);
        float inv = 1.0f / fmaxf(sqrtf(ss), 1e-12f);
        float f0x = v0.x*inv, f0y = v0.y*inv, f0z = v0.z*inv, f0w = v0.w*inv;
        float f1x = v1.x*inv, f1y = v1.y*inv, f1z = v1.z*inv, f1w = v1.w*inv;
        cs0[0] += f0x; cs0[1] += f0y; cs0[2] += f0z; cs0[3] += f0w;
        cs1[0] += f1x; cs1[1] += f1y; cs1[2] += f1z; cs1[3] += f1w;
        ushort4 o0, o1;
        o0.x = f2bf(f0x); o0.y = f2bf(f0y); o0.z = f2bf(f0z); o0.w = f2bf(f0w);
        o1.x = f2bf(f1x); o1.y = f2bf(f1y); o1.z = f2bf(f1z); o1.w = f2bf(f1w);
        ushort4* op = reinterpret_cast<ushort4*>(outp + (size_t)r * D_DIM);
        op[lane]      = o0;
        op[lane + 64] = o1;
    }

    // block-level colsum reduce: LDS atomics (4-way max contention), then one
    // global atomic per column per block, spread across 64B lines.
    __shared__ float csh[D_DIM];
    if (threadIdx.x < 256) { csh[threadIdx.x] = 0.f; csh[threadIdx.x + 256] = 0.f; }
    __syncthreads();
#pragma unroll
    for (int j = 0; j < 4; ++j) {
        atomicAdd(&csh[lane * 4 + j], cs0[j]);
        atomicAdd(&csh[256 + lane * 4 + j], cs1[j]);
    }
    __syncthreads();
    if (threadIdx.x < 256) {
        atomicAdd(&cs[(size_t)threadIdx.x * CS_STRIDE], csh[threadIdx.x]);
        atomicAdd(&cs[(size_t)(threadIdx.x + 256) * CS_STRIDE], csh[threadIdx.x + 256]);
    }
}

// ---------------- MFMA GEMM with fused epilogue ----------------
#define BM 128
#define BN 128
#define BK 64

typedef const __attribute__((address_space(1))) unsigned int* as1_u32p;
typedef __attribute__((address_space(3))) unsigned int* as3_u32p;

__device__ __forceinline__ void load_lds16(const void* g, void* l) {
    // each lane writes 16B at (wave-uniform l) + lane*16
    __builtin_amdgcn_global_load_lds((as1_u32p)g, (as3_u32p)l, 16, 0, 0);
}

// EPI==0: C = A@Bm^T, S[row] += sum_col exp(C*invT)          (neg pass)
// EPI==1: loss_sum += sum(-log(exp(C*invT)/(exp+S[row])+eps)) (pos pass)
template <int EPI>
__global__ __launch_bounds__(256, 4) void gemm_epi(const bf16* __restrict__ A,
                                                   const bf16* __restrict__ Bm,
                                                   float* __restrict__ S,
                                                   float* __restrict__ loss_sum) {
    __shared__ bf16 As[BM * BK];  // 16 KB, swizzled 16B granules
    __shared__ bf16 Bs[BN * BK];  // 16 KB

    const int tid  = threadIdx.x;
    const int lane = tid & 63;
    const int w    = tid >> 6;          // wave 0..3
    const int wm   = w >> 1, wn = w & 1;
    const int m0   = blockIdx.y * BM;
    const int n0   = blockIdx.x * BN;
    const int lr   = lane & 15;         // col-in-tile for frags
    const int q    = lane >> 4;         // quad 0..3

    floatx4 acc[4][4];
#pragma unroll
    for (int i = 0; i < 4; ++i)
#pragma unroll
        for (int j = 0; j < 4; ++j) acc[i][j] = (floatx4){0.f, 0.f, 0.f, 0.f};

    // staging: lane fetches row (rbase + lane>>3), 16B chunk (lane&7)^(lane>>3)
    // (XOR swizzle folded into gather; global_load_lds LDS dest is lane-contiguous)
    const int srow   = lane >> 3;            // 0..7
    const int schunk = (lane & 7) ^ srow;    // swizzled 16B chunk index 0..7

    for (int kt = 0; kt < D_DIM; kt += BK) {
        __syncthreads();  // prior ds_reads done before overwrite
#pragma unroll
        for (int i = 0; i < 4; ++i) {
            int rbase = w * 32 + i * 8;  // 8-aligned -> (row&7)==(lane>>3)
            const bf16* asrc = A + (size_t)(m0 + rbase + srow) * D_DIM + kt + schunk * 8;
            load_lds16(asrc, &As[rbase * BK]);
            const bf16* bsrc = Bm + (size_t)(n0 + rbase + srow) * D_DIM + kt + schunk * 8;
            load_lds16(bsrc, &Bs[rbase * BK]);
        }
        __syncthreads();  // staging drained (compiler emits vmcnt(0) before barrier)

#pragma unroll
        for (int ks = 0; ks < 2; ++ks) {
            short8 af[4], bfr[4];
            const int cl = ks * 4 + q;                 // 16B chunk within BK row
            const int so = (cl ^ (lane & 7)) * 8;      // unswizzle: row&7 == lane&7 here
#pragma unroll
            for (int rt = 0; rt < 4; ++rt) {
                int r = wm * 64 + rt * 16 + lr;
                af[rt] = *reinterpret_cast<const short8*>(&As[r * BK + so]);
            }
#pragma unroll
            for (int ct = 0; ct < 4; ++ct) {
                int r = wn * 64 + ct * 16 + lr;
                bfr[ct] = *reinterpret_cast<const short8*>(&Bs[r * BK + so]);
            }
#pragma unroll
            for (int rt = 0; rt < 4; ++rt)
#pragma unroll
                for (int ct = 0; ct < 4; ++ct)
                    acc[rt][ct] = __builtin_amdgcn_mfma_f32_16x16x32_bf16(af[rt], bfr[ct],
                                                                          acc[rt][ct], 0, 0, 0);
        }
    }

    // C/D layout: col = lane&15, row = (lane>>4)*4 + reg
    if (EPI == 0) {
#pragma unroll
        for (int rt = 0; rt < 4; ++rt) {
#pragma unroll
            for (int reg = 0; reg < 4; ++reg) {
                float v = 0.f;
#pragma unroll
                for (int ct = 0; ct < 4; ++ct) v += __expf(acc[rt][ct][reg] * INV_T);
                v += __shfl_xor(v, 1);
                v += __shfl_xor(v, 2);
                v += __shfl_xor(v, 4);
                v += __shfl_xor(v, 8);
                if (lr == 0) {
                    int row = m0 + wm * 64 + rt * 16 + q * 4 + reg;
                    atomicAdd(&S[row], v);
                }
            }
        }
    } else {
        float lsum = 0.f;
#pragma unroll
        for (int rt = 0; rt < 4; ++rt) {
#pragma unroll
            for (int reg = 0; reg < 4; ++reg) {
                int row = m0 + wm * 64 + rt * 16 + q * 4 + reg;
                float Sv = S[row];
#pragma unroll
                for (int ct = 0; ct < 4; ++ct) {
                    float pe = __expf(acc[rt][ct][reg] * INV_T);
                    lsum -= __logf(pe / (pe + Sv) + EPS_L);
                }
            }
        }
#pragma unroll
        for (int off = 1; off < 64; off <<= 1) lsum += __shfl_xor(lsum, off);
        if (lane == 0) atomicAdd(loss_sum, lsum);
    }
}

// ---- finalize: dot the (strided) column sums, emit the 4 scalars ----
__global__ void finalize_k(const float* __restrict__ csA, const float* __restrict__ csP,
                           const float* __restrict__ csN, const float* __restrict__ lsum,
                           float* __restrict__ out) {
    int tid = threadIdx.x;  // 512
    float av = csA[(size_t)tid * CS_STRIDE];
    float dp = av * csP[(size_t)tid * CS_STRIDE];
    float dn = av * csN[(size_t)tid * CS_STRIDE];
#pragma unroll
    for (int off = 1; off < 64; off <<= 1) {
        dp += __shfl_xor(dp, off);
        dn += __shfl_xor(dn, off);
    }
    __shared__ float red[16];
    int wid = tid >> 6, lane = tid & 63;
    if (lane == 0) { red[wid] = dp; red[8 + wid] = dn; }
    __syncthreads();
    if (tid == 0) {
        float sdp = 0.f, sdn = 0.f;
#pragma unroll
        for (int i = 0; i < 8; ++i) { sdp += red[i]; sdn += red[8 + i]; }
        float mean_pos = sdp * INV_T / ((float)B_ROWS * (float)P_ROWS);
        float mean_neg = sdn * INV_T / ((float)B_ROWS * (float)N_ROWS);
        out[0] = lsum[0] / ((float)B_ROWS * (float)P_ROWS);
        out[1] = mean_pos;
        out[2] = mean_neg;
        out[3] = mean_pos - mean_neg;
    }
}

extern "C" void kernel_launch(void* const* d_in, const int* in_sizes, int n_in,
                              void* d_out, int out_size, void* d_ws, size_t ws_size,
                              hipStream_t stream) {
    const float* anc = (const float*)d_in[0];
    const float* pos = (const float*)d_in[1];
    const float* neg = (const float*)d_in[2];
    float* out = (float*)d_out;

    bf16* aB = (bf16*)d_ws;
    bf16* pB = aB + (size_t)B_ROWS * D_DIM;
    bf16* nB = pB + (size_t)P_ROWS * D_DIM;
    float* fsec = (float*)(nB + (size_t)N_ROWS * D_DIM);  // 24MB offset, 64B-aligned
    float* S    = fsec;                        // 4096
    float* csA  = S + B_ROWS;                  // 512*16
    float* csP  = csA + D_DIM * CS_STRIDE;     // 512*16
    float* csN  = csP + D_DIM * CS_STRIDE;     // 512*16
    float* lsum = csN + D_DIM * CS_STRIDE;     // 1

    // ws is re-poisoned 0xAA before every launch -> zero all accumulators
    hipMemsetAsync(fsec, 0, (B_ROWS + 3 * D_DIM * CS_STRIDE + 1) * sizeof(float), stream);

    norm_colsum<<<1024, 256, 0, stream>>>(anc, pos, neg, aB, pB, nB, csA, csP, csN);

    gemm_epi<0><<<dim3(N_ROWS / BN, B_ROWS / BM), 256, 0, stream>>>(aB, nB, S, nullptr);
    gemm_epi<1><<<dim3(P_ROWS / BN, B_ROWS / BM), 256, 0, stream>>>(aB, pB, S, lsum);

    finalize_k<<<1, 512, 0, stream>>>(csA, csP, csN, lsum, out);
}

// Round 3
// 292.014 us; speedup vs baseline: 1.1766x; 1.0942x over previous
//
#include <hip/hip_runtime.h>
#include <hip/hip_bf16.h>

// InfoNCE: a[4096,512], p[4096,512], n[16384,512] f32 -> 4 f32 scalars.
// R3: fp8 e4m3 operands for the sim GEMMs (staging bytes halve -> MFMA-bound),
//     BK=128 fp8 elements (same 128B/row staging shape as bf16 BK=64), 4 K-iters.
//     Colsums (mean_pos/mean_neg) stay fp32-exact. Epilogue accs stay fp32.
// ws layout: a8(2MB) p8(2MB) n8(8MB) | S[4096] csA[512*16] csP[512*16] csN[512*16] lsum[1]

#define D_DIM 512
#define B_ROWS 4096
#define P_ROWS 4096
#define N_ROWS 16384
#define INV_T 14.285714285714286f
#define EPS_L 1e-8f
#define CS_STRIDE 16  // colsum accumulators spread 64B apart -> atomics hit distinct lines

typedef unsigned char fp8_t;
typedef __attribute__((ext_vector_type(4))) float floatx4;  // MFMA C/D frag
typedef unsigned int uint32;

// ---- fused: L2-normalize rows -> fp8 e4m3, and accumulate fp32 column sums ----
// grid = 1024 blocks x 256 thr. Segments: b<256 -> A, b<512 -> P, else -> N.
__global__ __launch_bounds__(256) void norm_colsum(
        const float* __restrict__ a, const float* __restrict__ p, const float* __restrict__ n,
        fp8_t* __restrict__ a8, fp8_t* __restrict__ p8, fp8_t* __restrict__ n8,
        float* __restrict__ csA, float* __restrict__ csP, float* __restrict__ csN) {
    const float* in; fp8_t* outp; float* cs; int rows, nb, bseg;
    int b = blockIdx.x;
    if (b < 256)      { in = a; outp = a8; cs = csA; rows = B_ROWS; nb = 256; bseg = b; }
    else if (b < 512) { in = p; outp = p8; cs = csP; rows = P_ROWS; nb = 256; bseg = b - 256; }
    else              { in = n; outp = n8; cs = csN; rows = N_ROWS; nb = 512; bseg = b - 512; }

    const int wave = threadIdx.x >> 6;
    const int lane = threadIdx.x & 63;

    float cs0[4] = {0.f, 0.f, 0.f, 0.f};
    float cs1[4] = {0.f, 0.f, 0.f, 0.f};

    for (int chunk = bseg; chunk < (rows >> 2); chunk += nb) {
        int r = chunk * 4 + wave;
        const float4* rp = reinterpret_cast<const float4*>(in + (size_t)r * D_DIM);
        float4 v0 = rp[lane];
        float4 v1 = rp[lane + 64];
        float ss = v0.x*v0.x + v0.y*v0.y + v0.z*v0.z + v0.w*v0.w
                 + v1.x*v1.x + v1.y*v1.y + v1.z*v1.z + v1.w*v1.w;
#pragma unroll
        for (int off = 1; off < 64; off <<= 1) ss += __shfl_xor(ss, off);
        float inv = 1.0f / fmaxf(sqrtf(ss), 1e-12f);
        float f0x = v0.x*inv, f0y = v0.y*inv, f0z = v0.z*inv, f0w = v0.w*inv;
        float f1x = v1.x*inv, f1y = v1.y*inv, f1z = v1.z*inv, f1w = v1.w*inv;
        cs0[0] += f0x; cs0[1] += f0y; cs0[2] += f0z; cs0[3] += f0w;
        cs1[0] += f1x; cs1[1] += f1y; cs1[2] += f1z; cs1[3] += f1w;
        // pack 4 floats -> 4 fp8 e4m3 bytes (RNE hw cvt)
        int pk0 = __builtin_amdgcn_cvt_pk_fp8_f32(f0x, f0y, 0, 0);
        pk0     = __builtin_amdgcn_cvt_pk_fp8_f32(f0z, f0w, pk0, 1);
        int pk1 = __builtin_amdgcn_cvt_pk_fp8_f32(f1x, f1y, 0, 0);
        pk1     = __builtin_amdgcn_cvt_pk_fp8_f32(f1z, f1w, pk1, 1);
        uint32* op = reinterpret_cast<uint32*>(outp + (size_t)r * D_DIM);
        op[lane]      = (uint32)pk0;   // bytes 4*lane .. 4*lane+3
        op[lane + 64] = (uint32)pk1;   // bytes 256+4*lane ..
    }

    // block-level colsum reduce: LDS atomics (4-way max contention), then one
    // global atomic per column per block, spread across 64B lines.
    __shared__ float csh[D_DIM];
    if (threadIdx.x < 256) { csh[threadIdx.x] = 0.f; csh[threadIdx.x + 256] = 0.f; }
    __syncthreads();
#pragma unroll
    for (int j = 0; j < 4; ++j) {
        atomicAdd(&csh[lane * 4 + j], cs0[j]);
        atomicAdd(&csh[256 + lane * 4 + j], cs1[j]);
    }
    __syncthreads();
    if (threadIdx.x < 256) {
        atomicAdd(&cs[(size_t)threadIdx.x * CS_STRIDE], csh[threadIdx.x]);
        atomicAdd(&cs[(size_t)(threadIdx.x + 256) * CS_STRIDE], csh[threadIdx.x + 256]);
    }
}

// ---------------- fp8 MFMA GEMM with fused epilogue ----------------
#define BM 128
#define BN 128
#define BKB 128  // K-elements per tile == bytes per row per tile (fp8)

typedef const __attribute__((address_space(1))) unsigned int* as1_u32p;
typedef __attribute__((address_space(3))) unsigned int* as3_u32p;

__device__ __forceinline__ void load_lds16(const void* g, void* l) {
    // each lane writes 16B at (wave-uniform l) + lane*16
    __builtin_amdgcn_global_load_lds((as1_u32p)g, (as3_u32p)l, 16, 0, 0);
}

// EPI==0: C = A@Bm^T, S[row] += sum_col exp(C*invT)           (neg pass)
// EPI==1: loss_sum += sum(-log(exp(C*invT)/(exp+S[row])+eps)) (pos pass)
template <int EPI>
__global__ __launch_bounds__(256, 4) void gemm_epi(const fp8_t* __restrict__ A,
                                                   const fp8_t* __restrict__ Bm,
                                                   float* __restrict__ S,
                                                   float* __restrict__ loss_sum) {
    __shared__ fp8_t As[BM * BKB];  // 16 KB, swizzled 16B granules
    __shared__ fp8_t Bs[BN * BKB];  // 16 KB

    const int tid  = threadIdx.x;
    const int lane = tid & 63;
    const int w    = tid >> 6;          // wave 0..3
    const int wm   = w >> 1, wn = w & 1;
    const int m0   = blockIdx.y * BM;
    const int n0   = blockIdx.x * BN;
    const int lr   = lane & 15;         // row-in-16-tile for frags
    const int q    = lane >> 4;         // quad 0..3

    floatx4 acc[4][4];
#pragma unroll
    for (int i = 0; i < 4; ++i)
#pragma unroll
        for (int j = 0; j < 4; ++j) acc[i][j] = (floatx4){0.f, 0.f, 0.f, 0.f};

    // staging: lane fetches row (rbase + lane>>3), 16B granule (lane&7)^(lane>>3)
    // (XOR swizzle folded into gather; global_load_lds LDS dest is lane-contiguous)
    const int srow   = lane >> 3;            // 0..7
    const int schunk = (lane & 7) ^ srow;    // swizzled 16B granule index 0..7

    for (int kt = 0; kt < D_DIM; kt += BKB) {
        __syncthreads();  // prior ds_reads done before overwrite
#pragma unroll
        for (int i = 0; i < 4; ++i) {
            int rbase = w * 32 + i * 8;  // 8-aligned -> (row&7)==(lane>>3)
            const fp8_t* asrc = A + (size_t)(m0 + rbase + srow) * D_DIM + kt + schunk * 16;
            load_lds16(asrc, &As[rbase * BKB]);
            const fp8_t* bsrc = Bm + (size_t)(n0 + rbase + srow) * D_DIM + kt + schunk * 16;
            load_lds16(bsrc, &Bs[rbase * BKB]);
        }
        __syncthreads();  // staging drained (compiler emits vmcnt(0) before barrier)

#pragma unroll
        for (int ks = 0; ks < 4; ++ks) {
            long af[4], bfr[4];
            // lane's K-window: k0 = ks*32 + q*8 (8 fp8 bytes); 16B granule g, 8B sub-offset
            const int g   = (ks * 32 + q * 8) >> 4;
            const int sub = (q & 1) * 8;
#pragma unroll
            for (int rt = 0; rt < 4; ++rt) {
                int r = wm * 64 + rt * 16 + lr;
                int off = ((g ^ (r & 7)) << 4) | sub;
                af[rt] = *reinterpret_cast<const long*>(&As[r * BKB + off]);
            }
#pragma unroll
            for (int ct = 0; ct < 4; ++ct) {
                int r = wn * 64 + ct * 16 + lr;
                int off = ((g ^ (r & 7)) << 4) | sub;
                bfr[ct] = *reinterpret_cast<const long*>(&Bs[r * BKB + off]);
            }
#pragma unroll
            for (int rt = 0; rt < 4; ++rt)
#pragma unroll
                for (int ct = 0; ct < 4; ++ct)
                    acc[rt][ct] = __builtin_amdgcn_mfma_f32_16x16x32_fp8_fp8(af[rt], bfr[ct],
                                                                             acc[rt][ct], 0, 0, 0);
        }
    }

    // C/D layout: col = lane&15, row = (lane>>4)*4 + reg
    if (EPI == 0) {
#pragma unroll
        for (int rt = 0; rt < 4; ++rt) {
#pragma unroll
            for (int reg = 0; reg < 4; ++reg) {
                float v = 0.f;
#pragma unroll
                for (int ct = 0; ct < 4; ++ct) v += __expf(acc[rt][ct][reg] * INV_T);
                v += __shfl_xor(v, 1);
                v += __shfl_xor(v, 2);
                v += __shfl_xor(v, 4);
                v += __shfl_xor(v, 8);
                if (lr == 0) {
                    int row = m0 + wm * 64 + rt * 16 + q * 4 + reg;
                    atomicAdd(&S[row], v);
                }
            }
        }
    } else {
        float lsum = 0.f;
#pragma unroll
        for (int rt = 0; rt < 4; ++rt) {
#pragma unroll
            for (int reg = 0; reg < 4; ++reg) {
                int row = m0 + wm * 64 + rt * 16 + q * 4 + reg;
                float Sv = S[row];
#pragma unroll
                for (int ct = 0; ct < 4; ++ct) {
                    float pe = __expf(acc[rt][ct][reg] * INV_T);
                    lsum -= __logf(pe / (pe + Sv) + EPS_L);
                }
            }
        }
#pragma unroll
        for (int off = 1; off < 64; off <<= 1) lsum += __shfl_xor(lsum, off);
        if (lane == 0) atomicAdd(loss_sum, lsum);
    }
}

// ---- finalize: dot the (strided) column sums, emit the 4 scalars ----
__global__ void finalize_k(const float* __restrict__ csA, const float* __restrict__ csP,
                           const float* __restrict__ csN, const float* __restrict__ lsum,
                           float* __restrict__ out) {
    int tid = threadIdx.x;  // 512
    float av = csA[(size_t)tid * CS_STRIDE];
    float dp = av * csP[(size_t)tid * CS_STRIDE];
    float dn = av * csN[(size_t)tid * CS_STRIDE];
#pragma unroll
    for (int off = 1; off < 64; off <<= 1) {
        dp += __shfl_xor(dp, off);
        dn += __shfl_xor(dn, off);
    }
    __shared__ float red[16];
    int wid = tid >> 6, lane = tid & 63;
    if (lane == 0) { red[wid] = dp; red[8 + wid] = dn; }
    __syncthreads();
    if (tid == 0) {
        float sdp = 0.f, sdn = 0.f;
#pragma unroll
        for (int i = 0; i < 8; ++i) { sdp += red[i]; sdn += red[8 + i]; }
        float mean_pos = sdp * INV_T / ((float)B_ROWS * (float)P_ROWS);
        float mean_neg = sdn * INV_T / ((float)B_ROWS * (float)N_ROWS);
        out[0] = lsum[0] / ((float)B_ROWS * (float)P_ROWS);
        out[1] = mean_pos;
        out[2] = mean_neg;
        out[3] = mean_pos - mean_neg;
    }
}

extern "C" void kernel_launch(void* const* d_in, const int* in_sizes, int n_in,
                              void* d_out, int out_size, void* d_ws, size_t ws_size,
                              hipStream_t stream) {
    const float* anc = (const float*)d_in[0];
    const float* pos = (const float*)d_in[1];
    const float* neg = (const float*)d_in[2];
    float* out = (float*)d_out;

    fp8_t* a8 = (fp8_t*)d_ws;
    fp8_t* p8 = a8 + (size_t)B_ROWS * D_DIM;
    fp8_t* n8 = p8 + (size_t)P_ROWS * D_DIM;
    float* fsec = (float*)(n8 + (size_t)N_ROWS * D_DIM);  // 12MB offset, 64B-aligned
    float* S    = fsec;                        // 4096
    float* csA  = S + B_ROWS;                  // 512*16
    float* csP  = csA + D_DIM * CS_STRIDE;     // 512*16
    float* csN  = csP + D_DIM * CS_STRIDE;     // 512*16
    float* lsum = csN + D_DIM * CS_STRIDE;     // 1

    // ws is re-poisoned 0xAA before every launch -> zero all accumulators
    hipMemsetAsync(fsec, 0, (B_ROWS + 3 * D_DIM * CS_STRIDE + 1) * sizeof(float), stream);

    norm_colsum<<<1024, 256, 0, stream>>>(anc, pos, neg, a8, p8, n8, csA, csP, csN);

    gemm_epi<0><<<dim3(N_ROWS / BN, B_ROWS / BM), 256, 0, stream>>>(a8, n8, S, nullptr);
    gemm_epi<1><<<dim3(P_ROWS / BN, B_ROWS / BM), 256, 0, stream>>>(a8, p8, S, lsum);

    finalize_k<<<1, 512, 0, stream>>>(csA, csP, csN, lsum, out);
}

// Round 4
// 284.688 us; speedup vs baseline: 1.2069x; 1.0257x over previous
//
#include <hip/hip_runtime.h>
#include <hip/hip_bf16.h>

// InfoNCE: a[4096,512], p[4096,512], n[16384,512] f32 -> 4 f32 scalars.
// R4: fp8 GEMM keeps BK=128, but fragment reads are ds_read_b128 with a
//     K-permutation (same for A and B -> dot product unchanged): lane reads
//     granule g=t*4+q (16B), low 8B feeds MFMA call 2t, high 8B call 2t+1.
//     This restores the conflict-free b128 LDS pattern (R3's b64 reads caused
//     8.4M bank-conflict cycles) and halves LDS instruction count.
// ws layout: a8(2MB) p8(2MB) n8(8MB) | S[4096] csA[512*16] csP[512*16] csN[512*16] lsum[1]

#define D_DIM 512
#define B_ROWS 4096
#define P_ROWS 4096
#define N_ROWS 16384
#define INV_T 14.285714285714286f
#define EPS_L 1e-8f
#define CS_STRIDE 16  // colsum accumulators spread 64B apart -> atomics hit distinct lines

typedef unsigned char fp8_t;
typedef __attribute__((ext_vector_type(4))) float floatx4;   // MFMA C/D frag
typedef __attribute__((ext_vector_type(2))) long longx2;     // 16B LDS read = 2 MFMA operands
typedef unsigned int uint32;

// ---- fused: L2-normalize rows -> fp8 e4m3, and accumulate fp32 column sums ----
// grid = 1024 blocks x 256 thr. Segments: b<256 -> A, b<512 -> P, else -> N.
__global__ __launch_bounds__(256) void norm_colsum(
        const float* __restrict__ a, const float* __restrict__ p, const float* __restrict__ n,
        fp8_t* __restrict__ a8, fp8_t* __restrict__ p8, fp8_t* __restrict__ n8,
        float* __restrict__ csA, float* __restrict__ csP, float* __restrict__ csN) {
    const float* in; fp8_t* outp; float* cs; int rows, nb, bseg;
    int b = blockIdx.x;
    if (b < 256)      { in = a; outp = a8; cs = csA; rows = B_ROWS; nb = 256; bseg = b; }
    else if (b < 512) { in = p; outp = p8; cs = csP; rows = P_ROWS; nb = 256; bseg = b - 256; }
    else              { in = n; outp = n8; cs = csN; rows = N_ROWS; nb = 512; bseg = b - 512; }

    const int wave = threadIdx.x >> 6;
    const int lane = threadIdx.x & 63;

    float cs0[4] = {0.f, 0.f, 0.f, 0.f};
    float cs1[4] = {0.f, 0.f, 0.f, 0.f};

    for (int chunk = bseg; chunk < (rows >> 2); chunk += nb) {
        int r = chunk * 4 + wave;
        const float4* rp = reinterpret_cast<const float4*>(in + (size_t)r * D_DIM);
        float4 v0 = rp[lane];
        float4 v1 = rp[lane + 64];
        float ss = v0.x*v0.x + v0.y*v0.y + v0.z*v0.z + v0.w*v0.w
                 + v1.x*v1.x + v1.y*v1.y + v1.z*v1.z + v1.w*v1.w;
#pragma unroll
        for (int off = 1; off < 64; off <<= 1) ss += __shfl_xor(ss, off);
        float inv = 1.0f / fmaxf(sqrtf(ss), 1e-12f);
        float f0x = v0.x*inv, f0y = v0.y*inv, f0z = v0.z*inv, f0w = v0.w*inv;
        float f1x = v1.x*inv, f1y = v1.y*inv, f1z = v1.z*inv, f1w = v1.w*inv;
        cs0[0] += f0x; cs0[1] += f0y; cs0[2] += f0z; cs0[3] += f0w;
        cs1[0] += f1x; cs1[1] += f1y; cs1[2] += f1z; cs1[3] += f1w;
        // pack 4 floats -> 4 fp8 e4m3 bytes (RNE hw cvt)
        int pk0 = __builtin_amdgcn_cvt_pk_fp8_f32(f0x, f0y, 0, 0);
        pk0     = __builtin_amdgcn_cvt_pk_fp8_f32(f0z, f0w, pk0, 1);
        int pk1 = __builtin_amdgcn_cvt_pk_fp8_f32(f1x, f1y, 0, 0);
        pk1     = __builtin_amdgcn_cvt_pk_fp8_f32(f1z, f1w, pk1, 1);
        uint32* op = reinterpret_cast<uint32*>(outp + (size_t)r * D_DIM);
        op[lane]      = (uint32)pk0;   // bytes 4*lane .. 4*lane+3
        op[lane + 64] = (uint32)pk1;   // bytes 256+4*lane ..
    }

    // block-level colsum reduce: LDS atomics (4-way max contention), then one
    // global atomic per column per block, spread across 64B lines.
    __shared__ float csh[D_DIM];
    if (threadIdx.x < 256) { csh[threadIdx.x] = 0.f; csh[threadIdx.x + 256] = 0.f; }
    __syncthreads();
#pragma unroll
    for (int j = 0; j < 4; ++j) {
        atomicAdd(&csh[lane * 4 + j], cs0[j]);
        atomicAdd(&csh[256 + lane * 4 + j], cs1[j]);
    }
    __syncthreads();
    if (threadIdx.x < 256) {
        atomicAdd(&cs[(size_t)threadIdx.x * CS_STRIDE], csh[threadIdx.x]);
        atomicAdd(&cs[(size_t)(threadIdx.x + 256) * CS_STRIDE], csh[threadIdx.x + 256]);
    }
}

// ---------------- fp8 MFMA GEMM with fused epilogue ----------------
#define BM 128
#define BN 128
#define BKB 128  // K-elements per tile == bytes per row per tile (fp8)

typedef const __attribute__((address_space(1))) unsigned int* as1_u32p;
typedef __attribute__((address_space(3))) unsigned int* as3_u32p;

__device__ __forceinline__ void load_lds16(const void* g, void* l) {
    // each lane writes 16B at (wave-uniform l) + lane*16
    __builtin_amdgcn_global_load_lds((as1_u32p)g, (as3_u32p)l, 16, 0, 0);
}

// EPI==0: C = A@Bm^T, S[row] += sum_col exp(C*invT)           (neg pass)
// EPI==1: loss_sum += sum(-log(exp(C*invT)/(exp+S[row])+eps)) (pos pass)
template <int EPI>
__global__ __launch_bounds__(256, 4) void gemm_epi(const fp8_t* __restrict__ A,
                                                   const fp8_t* __restrict__ Bm,
                                                   float* __restrict__ S,
                                                   float* __restrict__ loss_sum) {
    __shared__ fp8_t As[BM * BKB];  // 16 KB, swizzled 16B granules
    __shared__ fp8_t Bs[BN * BKB];  // 16 KB

    const int tid  = threadIdx.x;
    const int lane = tid & 63;
    const int w    = tid >> 6;          // wave 0..3
    const int wm   = w >> 1, wn = w & 1;
    const int m0   = blockIdx.y * BM;
    const int n0   = blockIdx.x * BN;
    const int lr   = lane & 15;         // row-in-16-tile for frags
    const int q    = lane >> 4;         // quad 0..3

    floatx4 acc[4][4];
#pragma unroll
    for (int i = 0; i < 4; ++i)
#pragma unroll
        for (int j = 0; j < 4; ++j) acc[i][j] = (floatx4){0.f, 0.f, 0.f, 0.f};

    // staging: lane fetches row (rbase + lane>>3), 16B granule (lane&7)^(lane>>3)
    // (XOR swizzle folded into gather; global_load_lds LDS dest is lane-contiguous)
    const int srow   = lane >> 3;            // 0..7
    const int schunk = (lane & 7) ^ srow;    // swizzled 16B granule index 0..7

    for (int kt = 0; kt < D_DIM; kt += BKB) {
        __syncthreads();  // prior ds_reads done before overwrite
#pragma unroll
        for (int i = 0; i < 4; ++i) {
            int rbase = w * 32 + i * 8;  // 8-aligned -> (row&7)==(lane>>3)
            const fp8_t* asrc = A + (size_t)(m0 + rbase + srow) * D_DIM + kt + schunk * 16;
            load_lds16(asrc, &As[rbase * BKB]);
            const fp8_t* bsrc = Bm + (size_t)(n0 + rbase + srow) * D_DIM + kt + schunk * 16;
            load_lds16(bsrc, &Bs[rbase * BKB]);
        }
        __syncthreads();  // staging drained (compiler emits vmcnt(0) before barrier)

        // K-permuted fragment reads: lane reads granule g = t*4+q (b128,
        // conflict-free phase pattern), halves feed MFMA calls 2t and 2t+1.
        // Same (t,q,h)->k mapping for A and B => dot product is exact.
#pragma unroll
        for (int t = 0; t < 2; ++t) {
            longx2 af[4], bfr[4];
            const int g = t * 4 + q;
#pragma unroll
            for (int rt = 0; rt < 4; ++rt) {
                int r = wm * 64 + rt * 16 + lr;
                int off = (g ^ (r & 7)) << 4;
                af[rt] = *reinterpret_cast<const longx2*>(&As[r * BKB + off]);
            }
#pragma unroll
            for (int ct = 0; ct < 4; ++ct) {
                int r = wn * 64 + ct * 16 + lr;
                int off = (g ^ (r & 7)) << 4;
                bfr[ct] = *reinterpret_cast<const longx2*>(&Bs[r * BKB + off]);
            }
#pragma unroll
            for (int rt = 0; rt < 4; ++rt)
#pragma unroll
                for (int ct = 0; ct < 4; ++ct)
                    acc[rt][ct] = __builtin_amdgcn_mfma_f32_16x16x32_fp8_fp8(af[rt].x, bfr[ct].x,
                                                                             acc[rt][ct], 0, 0, 0);
#pragma unroll
            for (int rt = 0; rt < 4; ++rt)
#pragma unroll
                for (int ct = 0; ct < 4; ++ct)
                    acc[rt][ct] = __builtin_amdgcn_mfma_f32_16x16x32_fp8_fp8(af[rt].y, bfr[ct].y,
                                                                             acc[rt][ct], 0, 0, 0);
        }
    }

    // C/D layout: col = lane&15, row = (lane>>4)*4 + reg
    if (EPI == 0) {
#pragma unroll
        for (int rt = 0; rt < 4; ++rt) {
#pragma unroll
            for (int reg = 0; reg < 4; ++reg) {
                float v = 0.f;
#pragma unroll
                for (int ct = 0; ct < 4; ++ct) v += __expf(acc[rt][ct][reg] * INV_T);
                v += __shfl_xor(v, 1);
                v += __shfl_xor(v, 2);
                v += __shfl_xor(v, 4);
                v += __shfl_xor(v, 8);
                if (lr == 0) {
                    int row = m0 + wm * 64 + rt * 16 + q * 4 + reg;
                    atomicAdd(&S[row], v);
                }
            }
        }
    } else {
        float lsum = 0.f;
#pragma unroll
        for (int rt = 0; rt < 4; ++rt) {
#pragma unroll
            for (int reg = 0; reg < 4; ++reg) {
                int row = m0 + wm * 64 + rt * 16 + q * 4 + reg;
                float Sv = S[row];
#pragma unroll
                for (int ct = 0; ct < 4; ++ct) {
                    float pe = __expf(acc[rt][ct][reg] * INV_T);
                    lsum -= __logf(pe / (pe + Sv) + EPS_L);
                }
            }
        }
#pragma unroll
        for (int off = 1; off < 64; off <<= 1) lsum += __shfl_xor(lsum, off);
        if (lane == 0) atomicAdd(loss_sum, lsum);
    }
}

// ---- finalize: dot the (strided) column sums, emit the 4 scalars ----
__global__ void finalize_k(const float* __restrict__ csA, const float* __restrict__ csP,
                           const float* __restrict__ csN, const float* __restrict__ lsum,
                           float* __restrict__ out) {
    int tid = threadIdx.x;  // 512
    float av = csA[(size_t)tid * CS_STRIDE];
    float dp = av * csP[(size_t)tid * CS_STRIDE];
    float dn = av * csN[(size_t)tid * CS_STRIDE];
#pragma unroll
    for (int off = 1; off < 64; off <<= 1) {
        dp += __shfl_xor(dp, off);
        dn += __shfl_xor(dn, off);
    }
    __shared__ float red[16];
    int wid = tid >> 6, lane = tid & 63;
    if (lane == 0) { red[wid] = dp; red[8 + wid] = dn; }
    __syncthreads();
    if (tid == 0) {
        float sdp = 0.f, sdn = 0.f;
#pragma unroll
        for (int i = 0; i < 8; ++i) { sdp += red[i]; sdn += red[8 + i]; }
        float mean_pos = sdp * INV_T / ((float)B_ROWS * (float)P_ROWS);
        float mean_neg = sdn * INV_T / ((float)B_ROWS * (float)N_ROWS);
        out[0] = lsum[0] / ((float)B_ROWS * (float)P_ROWS);
        out[1] = mean_pos;
        out[2] = mean_neg;
        out[3] = mean_pos - mean_neg;
    }
}

extern "C" void kernel_launch(void* const* d_in, const int* in_sizes, int n_in,
                              void* d_out, int out_size, void* d_ws, size_t ws_size,
                              hipStream_t stream) {
    const float* anc = (const float*)d_in[0];
    const float* pos = (const float*)d_in[1];
    const float* neg = (const float*)d_in[2];
    float* out = (float*)d_out;

    fp8_t* a8 = (fp8_t*)d_ws;
    fp8_t* p8 = a8 + (size_t)B_ROWS * D_DIM;
    fp8_t* n8 = p8 + (size_t)P_ROWS * D_DIM;
    float* fsec = (float*)(n8 + (size_t)N_ROWS * D_DIM);  // 12MB offset, 64B-aligned
    float* S    = fsec;                        // 4096
    float* csA  = S + B_ROWS;                  // 512*16
    float* csP  = csA + D_DIM * CS_STRIDE;     // 512*16
    float* csN  = csP + D_DIM * CS_STRIDE;     // 512*16
    float* lsum = csN + D_DIM * CS_STRIDE;     // 1

    // ws is re-poisoned 0xAA before every launch -> zero all accumulators
    hipMemsetAsync(fsec, 0, (B_ROWS + 3 * D_DIM * CS_STRIDE + 1) * sizeof(float), stream);

    norm_colsum<<<1024, 256, 0, stream>>>(anc, pos, neg, a8, p8, n8, csA, csP, csN);

    gemm_epi<0><<<dim3(N_ROWS / BN, B_ROWS / BM), 256, 0, stream>>>(a8, n8, S, nullptr);
    gemm_epi<1><<<dim3(P_ROWS / BN, B_ROWS / BM), 256, 0, stream>>>(a8, p8, S, lsum);

    finalize_k<<<1, 512, 0, stream>>>(csA, csP, csN, lsum, out);
}